// Round 10
// baseline (165.947 us; speedup 1.0000x reference)
//
#include <hip/hip_runtime.h>
#include <math.h>

// (B,P,V,F,H) = (32,512,32,16,64). Round 10: remove the WF re-fetch invariant.
// r5/r7/r8/r9 all plateau at ~46us with one shared term: 36 frags x 1KB per bp
// re-fetched from global = 590 MB VMEM traffic (L1-thrashing). Fix: r8's
// 2-wave col-split block + a bp-loop (8 bp per block, grid 2048), with each
// wave holding its OWN 32-col weight slice in registers: 18 frags = 72 VGPRs
// (half of r4's failed 144), lean r9 epilogue, peak ~160 regs under the
// (128,3) cap of 170 => no spill, 3 waves/SIMD. WF traffic amortizes 8x.
// xb/pl ping-pong across iterations (partner-wave WAR); 3 barriers per bp.
// MFMA 16x16x32 bf16: A[m=lane&15][k=quad*8+j], B[k=quad*8+j][n=lane&15],
//                     D[row=quad*4+reg][col=lane&15]  (verified rounds 2-9).
namespace {
constexpr int kXS = 72;
constexpr float kSlope = 0.01f;

typedef short bf16x8 __attribute__((ext_vector_type(8)));
typedef float f32x4  __attribute__((ext_vector_type(4)));
typedef float f32x4v __attribute__((ext_vector_type(4)));
typedef int   i32x4v __attribute__((ext_vector_type(4)));

__device__ __forceinline__ float lrelu(float x) { return fmaxf(x, kSlope * x); }

__device__ __forceinline__ unsigned short bfrne(float a) {
    union { float f; unsigned u; } v; v.f = a;
    return (unsigned short)((v.u + 0x7FFFu + ((v.u >> 16) & 1u)) >> 16);
}
__device__ __forceinline__ short2 cvtpk(float a, float b) {
#if __has_builtin(__builtin_amdgcn_cvt_pk_bf16_f32)
    auto p = __builtin_amdgcn_cvt_pk_bf16_f32(a, b);
    short2 s; __builtin_memcpy(&s, &p, sizeof(s)); return s;
#else
    short2 s; s.x = (short)bfrne(a); s.y = (short)bfrne(b); return s;
#endif
}
__device__ __forceinline__ int cvtpk_i(float a, float b) {
    short2 s = cvtpk(a, b);
    int r; __builtin_memcpy(&r, &s, sizeof(r)); return r;
}

// ---- pre-pass: pack W1/W2/W3 as bf16 MFMA B-frags into d_ws ----
// frag f: 0..3 = W1 (nt=f, K=16 zero-padded); 4..19 = W2 (nt=(f-4)>>2,
// ks=(f-4)&3); 20..35 = W3. Lane l of frag f lives at ws[f*512 + l*8 ..+7].
__global__ void prep_weights(const float* __restrict__ W1,
                             const float* __restrict__ W2,
                             const float* __restrict__ W3,
                             unsigned short* __restrict__ ws)
{
    int t = blockIdx.x * blockDim.x + threadIdx.x;
    if (t >= 36 * 64) return;
    int f = t >> 6, l = t & 63, c = l & 15, q = l >> 4;
    unsigned short v[8] = {0, 0, 0, 0, 0, 0, 0, 0};
    const float* src = nullptr; int row = 0, k0 = 0, K = 0;
    if (f < 4) {
        if (q < 2) { src = W1; row = 16 * f + c; k0 = q * 8; K = 16; }
    } else if (f < 20) {
        int g = f - 4;  src = W2; row = 16 * (g >> 2) + c; k0 = (g & 3) * 32 + q * 8; K = 128;
    } else {
        int g = f - 20; src = W3; row = 16 * (g >> 2) + c; k0 = (g & 3) * 32 + q * 8; K = 128;
    }
    if (src) {
        #pragma unroll
        for (int j = 0; j < 8; ++j) v[j] = bfrne(src[row * K + k0 + j]);
    }
    unsigned short* dst = ws + (size_t)f * 512 + l * 8;
    *(ushort4*)(dst)     = make_ushort4(v[0], v[1], v[2], v[3]);
    *(ushort4*)(dst + 4) = make_ushort4(v[4], v[5], v[6], v[7]);
}

__global__ __launch_bounds__(128, 3) void fused_mlp_v10(
    const float* __restrict__ X, const int* __restrict__ M,
    const unsigned short* __restrict__ WF,
    const float* __restrict__ B1, const float* __restrict__ B2,
    const float* __restrict__ B3, float* __restrict__ OUT)
{
    __shared__ __align__(16) short xb[2][32 * kXS];  // ping-pong across bp iters
    __shared__ __align__(16) short pl[2][64];

    const int t = threadIdx.x, u = t >> 6, l = t & 63, c = l & 15, q = l >> 4;
    const int nb = 32 * u;                        // this wave's col base

    // ---- persistent per-wave weight slice: 18 frags = 72 VGPRs ----
    bf16x8 w1f[2], w2f[2][4], w3f[2][4];
    #pragma unroll
    for (int nt = 0; nt < 2; ++nt) {
        const int ng = 2 * u + nt;
        w1f[nt] = *(const bf16x8*)(WF + (size_t)ng * 512 + l * 8);
        #pragma unroll
        for (int ks = 0; ks < 4; ++ks) {
            w2f[nt][ks] = *(const bf16x8*)(WF + (size_t)(4 + ng * 4 + ks) * 512 + l * 8);
            w3f[nt][ks] = *(const bf16x8*)(WF + (size_t)(20 + ng * 4 + ks) * 512 + l * 8);
        }
    }
    float b1[2], b2[2], b3[2];
    #pragma unroll
    for (int nt = 0; nt < 2; ++nt) {
        b1[nt] = B1[nb + 16 * nt + c];
        b2[nt] = B2[nb + 16 * nt + c];
        b3[nt] = B3[nb + 16 * nt + c];
    }

    size_t bp = (size_t)blockIdx.x;
    f32x4v xr[2][2];
    i32x4v mr0, mr1;
    {   // prefetch iteration 0
        if (q < 2) {
            #pragma unroll
            for (int mt = 0; mt < 2; ++mt) {
                const f32x4v* p = (const f32x4v*)(X + (bp * 32 + 16 * mt + c) * 16 + q * 8);
                xr[mt][0] = __builtin_nontemporal_load(p);
                xr[mt][1] = __builtin_nontemporal_load(p + 1);
            }
        }
        const i32x4v* Mp = (const i32x4v*)(M + bp * 32);
        mr0 = __builtin_nontemporal_load(Mp + q);
        mr1 = __builtin_nontemporal_load(Mp + 4 + q);
    }

    f32x4 acc[2][2];

    #pragma unroll 1
    for (int it = 0; it < 8; ++it) {
        const size_t bp_cur = bp;
        short* xbc = &xb[it & 1][0];
        short* plc = &pl[it & 1][0];

        // consume current prefetch regs
        const unsigned mbits =
            (mr0[0] ? 1u : 0u)  | (mr0[1] ? 2u : 0u)  | (mr0[2] ? 4u : 0u)  | (mr0[3] ? 8u : 0u) |
            (mr1[0] ? 16u : 0u) | (mr1[1] ? 32u : 0u) | (mr1[2] ? 64u : 0u) | (mr1[3] ? 128u : 0u);
        const bool anyv = __any(mbits != 0);
        float mz[8], mn[8];
        #pragma unroll
        for (int i = 0; i < 8; ++i) {
            bool mk = (mbits >> i) & 1;
            mz[i] = mk ? 1.f : 0.f;
            mn[i] = mk ? 0.f : -INFINITY;
        }
        bf16x8 a1f[2];
        #pragma unroll
        for (int mt = 0; mt < 2; ++mt) {
            union { bf16x8 v; int i[4]; } uu;
            uu.v = bf16x8{};
            if (q < 2) {
                f32x4v f0 = xr[mt][0], f1 = xr[mt][1];
                uu.i[0] = cvtpk_i(f0[0], f0[1]);
                uu.i[1] = cvtpk_i(f0[2], f0[3]);
                uu.i[2] = cvtpk_i(f1[0], f1[1]);
                uu.i[3] = cvtpk_i(f1[2], f1[3]);
            }
            a1f[mt] = uu.v;
        }

        if (it < 7) {   // software-pipelined prefetch of next bp
            bp += 2048;
            if (q < 2) {
                #pragma unroll
                for (int mt = 0; mt < 2; ++mt) {
                    const f32x4v* p = (const f32x4v*)(X + (bp * 32 + 16 * mt + c) * 16 + q * 8);
                    xr[mt][0] = __builtin_nontemporal_load(p);
                    xr[mt][1] = __builtin_nontemporal_load(p + 1);
                }
            }
            const i32x4v* Mp = (const i32x4v*)(M + bp * 32);
            mr0 = __builtin_nontemporal_load(Mp + q);
            mr1 = __builtin_nontemporal_load(Mp + 4 + q);
        }

        // ---- layer 1 (K=16 zero-padded to 32), weights in registers ----
        #pragma unroll
        for (int nt = 0; nt < 2; ++nt) {
            f32x4 c0 = { b1[nt], b1[nt], b1[nt], b1[nt] };
            acc[0][nt] = __builtin_amdgcn_mfma_f32_16x16x32_bf16(a1f[0], w1f[nt], c0, 0, 0, 0);
            acc[1][nt] = __builtin_amdgcn_mfma_f32_16x16x32_bf16(a1f[1], w1f[nt], c0, 0, 0, 0);
        }

        // ---- epilogue: lrelu, o=y*mz, pool-cand=y+mn, packed cvt writes ----
        auto epilogue = [&]() {
            float pool[2];
            #pragma unroll
            for (int nt = 0; nt < 2; ++nt) {
                float pv = -INFINITY;
                #pragma unroll
                for (int mt = 0; mt < 2; ++mt) {
                    short* base = &xbc[(16 * mt + 4 * q) * kXS + nb + 16 * nt + c];
                    float o[4];
                    #pragma unroll
                    for (int r = 0; r < 4; ++r) {
                        float y = lrelu(acc[mt][nt][r]);
                        o[r] = y * mz[mt * 4 + r];
                        pv = fmaxf(pv, y + mn[mt * 4 + r]);
                    }
                    short2 s01 = cvtpk(o[0], o[1]);
                    short2 s23 = cvtpk(o[2], o[3]);
                    base[0 * kXS] = s01.x; base[1 * kXS] = s01.y;
                    base[2 * kXS] = s23.x; base[3 * kXS] = s23.y;
                }
                pv = fmaxf(pv, __shfl_xor(pv, 16));
                pv = fmaxf(pv, __shfl_xor(pv, 32));
                pool[nt] = anyv ? pv : 0.f;
            }
            if (q < 2) plc[nb + 16 * q + c] = (short)bfrne(q ? pool[1] : pool[0]);
        };

        // ---- K=128 layer: A-frags span both col halves; W in registers ----
        auto layerK = [&](const bf16x8 (&wf)[2][4], const float (&bv)[2]) {
            bf16x8 a00 = *(const bf16x8*)&xbc[(     c) * kXS      + q * 8];
            bf16x8 a01 = *(const bf16x8*)&xbc[(16 + c) * kXS      + q * 8];
            bf16x8 a10 = *(const bf16x8*)&xbc[(     c) * kXS + 32 + q * 8];
            bf16x8 a11 = *(const bf16x8*)&xbc[(16 + c) * kXS + 32 + q * 8];
            bf16x8 ap0 = *(const bf16x8*)&plc[q * 8];        // quad-broadcast
            bf16x8 ap1 = *(const bf16x8*)&plc[32 + q * 8];
            #pragma unroll
            for (int nt = 0; nt < 2; ++nt) {
                acc[0][nt] = f32x4{ bv[nt], bv[nt], bv[nt], bv[nt] };
                acc[1][nt] = acc[0][nt];
            }
            #pragma unroll
            for (int ks = 0; ks < 4; ++ks) {
                bf16x8 am0 = (ks == 0) ? a00 : (ks == 1) ? a10 : (ks == 2) ? ap0 : ap1;
                bf16x8 am1 = (ks == 0) ? a01 : (ks == 1) ? a11 : (ks == 2) ? ap0 : ap1;
                #pragma unroll
                for (int nt = 0; nt < 2; ++nt) {
                    acc[0][nt] = __builtin_amdgcn_mfma_f32_16x16x32_bf16(am0, wf[nt][ks], acc[0][nt], 0, 0, 0);
                    acc[1][nt] = __builtin_amdgcn_mfma_f32_16x16x32_bf16(am1, wf[nt][ks], acc[1][nt], 0, 0, 0);
                }
            }
        };

        epilogue();            // x2 = [out1 | pool1] into buffer it&1
        __syncthreads();       // writes visible to partner wave
        layerK(w2f, b2);       // layer 2
        __syncthreads();       // partner's reads done before overwrite (WAR)
        epilogue();            // x3 in place
        __syncthreads();       // writes visible
        layerK(w3f, b3);       // layer 3
        // (next iter's epilogue targets buffer (it+1)&1 -> no WAR with
        //  partner's layer-3 reads of buffer it&1; buffer it&1 is reused at
        //  it+2, by which time 3 barriers have passed)

        // ---- layer-3 pool == final output ----
        #pragma unroll
        for (int nt = 0; nt < 2; ++nt) {
            float pv = -INFINITY;
            #pragma unroll
            for (int mt = 0; mt < 2; ++mt)
                #pragma unroll
                for (int r = 0; r < 4; ++r) {
                    float y = lrelu(acc[mt][nt][r]);
                    pv = fmaxf(pv, y + mn[mt * 4 + r]);
                }
            pv = fmaxf(pv, __shfl_xor(pv, 16));
            pv = fmaxf(pv, __shfl_xor(pv, 32));
            pv = anyv ? pv : 0.f;
            if (q == 0) __builtin_nontemporal_store(pv, &OUT[bp_cur * 64 + nb + 16 * nt + c]);
        }
    }
}
} // namespace

extern "C" void kernel_launch(void* const* d_in, const int* in_sizes, int n_in,
                              void* d_out, int out_size, void* d_ws, size_t ws_size,
                              hipStream_t stream) {
    (void)in_sizes; (void)n_in; (void)ws_size; (void)out_size;
    const float* X  = (const float*)d_in[0];
    const int*   M  = (const int*)d_in[1];
    const float* W1 = (const float*)d_in[2];
    const float* B1 = (const float*)d_in[3];
    const float* W2 = (const float*)d_in[4];
    const float* B2 = (const float*)d_in[5];
    const float* W3 = (const float*)d_in[6];
    const float* B3 = (const float*)d_in[7];
    float* OUT = (float*)d_out;
    unsigned short* WF = (unsigned short*)d_ws;   // needs 36 KB of scratch

    prep_weights<<<(36 * 64 + 255) / 256, 256, 0, stream>>>(W1, W2, W3, WF);
    // 2048 blocks x 2 waves; each block loops over 8 bp (stride 2048)
    fused_mlp_v10<<<2048, 128, 0, stream>>>(X, M, WF, B1, B2, B3, OUT);
}